// Round 6
// baseline (154.271 us; speedup 1.0000x reference)
//
#include <hip/hip_runtime.h>
#include <math.h>

#define N_SAMPLES 131072
#define NUM_CLASSES 128
#define NB 256
#define MAX_FPR 0.7f          // 1 - RECALL_THRESHOLD
#define NBLK 256              // grid; 1 block/CU, all co-resident
#define ROWS_PER_BLK 512
#define HPITCH 129            // +1 word pad per class row (bank spread)

typedef unsigned long long u64;
typedef unsigned int u32;

// bin(x; L) = floor((x - L + 14) * 16) clamped to [0,255]. Identical
// expression for the positive and the all histogram.
__device__ __forceinline__ int bin_of(float x, float off /* (14-lse)*16 */) {
    int b = (int)__fmaf_rn(x, 16.0f, off);
    return min(max(b, 0), NB - 1);
}

// ---------------------------------------------------------------------------
// Single fused kernel.
// Phase 1: block = 512 rows, full 128x256 LDS histogram (u16 pairs in u32;
//   per-block counts <= 512, no carry). 16 lanes/row, 8 cols/lane via two
//   coalesced float4 loads; 2-deep software pipeline hides HBM latency.
// Merge: skip-zero u64 global atomicAdd into hAll (2 packed u32 counts) —
//   device-scope atomics are cross-XCD coherent (no plain-store hazard).
// Phase 2: done-counter spin (all NBLK blocks co-resident at 1/CU; blocks
//   >=128 retire so no deadlock); blocks 0..127 reduce one class each via
//   agent-scope atomic loads; last ticket writes the final scalar.
// ---------------------------------------------------------------------------
__global__ __launch_bounds__(1024, 4) void fused_all(
    const float* __restrict__ pred, const int* __restrict__ tgt,
    u64* __restrict__ hAll,      // [128][128] u64, pre-zeroed
    u32* __restrict__ hPos,      // [128][256] u32, pre-zeroed
    float* __restrict__ acc,     // [0]=ce [1]=pauc [2]=valid [3]=ctr1 [4]=ctr2
    float* __restrict__ out)
{
    __shared__ u32 h32[NUM_CLASSES * HPITCH];   // 66048 B
    __shared__ float wsum[16];

    const int tid  = threadIdx.x;
    const int w    = tid >> 6;        // wave 0..15
    const int lane = tid & 63;
    const int j    = lane & 15;       // lane within row
    const int rs   = lane >> 4;       // row sub-index 0..3

    for (int i = tid; i < NUM_CLASSES * HPITCH; i += 1024) h32[i] = 0u;
    __syncthreads();

    const int rowBase = blockIdx.x * ROWS_PER_BLK + w * 4 + rs;
    float acc_lse = 0.0f, acc_xt = 0.0f, acc_sx = 0.0f;

    // 2-deep pipeline over 8 passes (row stride 64 per pass)
    const float* r0p = pred + (size_t)rowBase * 128;
    float4 a0 = *(const float4*)(r0p + j * 4);
    float4 a1 = *(const float4*)(r0p + 64 + j * 4);
    int    ta = tgt[rowBase];
    const float* r1p = r0p + (size_t)64 * 128;
    float4 c0 = *(const float4*)(r1p + j * 4);
    float4 c1 = *(const float4*)(r1p + 64 + j * 4);
    int    tb = tgt[rowBase + 64];

    #pragma unroll
    for (int p = 0; p < 8; p++) {
        float4 n0, n1; int tn = 0;
        if (p < 6) {
            const float* rn = pred + (size_t)(rowBase + (p + 2) * 64) * 128;
            n0 = *(const float4*)(rn + j * 4);
            n1 = *(const float4*)(rn + 64 + j * 4);
            tn = tgt[rowBase + (p + 2) * 64];
        }

        float e = __expf(a0.x) + __expf(a0.y) + __expf(a0.z) + __expf(a0.w)
                + __expf(a1.x) + __expf(a1.y) + __expf(a1.z) + __expf(a1.w);
        #pragma unroll
        for (int o = 1; o < 16; o <<= 1) e += __shfl_xor(e, o);
        const float lse = __logf(e);
        const float off = (14.0f - lse) * 16.0f;

        const float xv[8] = {a0.x, a0.y, a0.z, a0.w, a1.x, a1.y, a1.z, a1.w};
        #pragma unroll
        for (int q = 0; q < 8; q++) {
            const int c = (q < 4) ? (j * 4 + q) : (64 + j * 4 + (q - 4));
            const int b = bin_of(xv[q], off);
            atomicAdd(&h32[c * HPITCH + (b >> 1)], (b & 1) ? 65536u : 1u);
        }

        acc_sx  += (xv[0] + xv[1] + xv[2] + xv[3])
                 + (xv[4] + xv[5] + xv[6] + xv[7]);
        acc_lse += lse * 0.0625f;     // 16 lanes/row each add lse/16

        {   // exactly one of the row's 16 lanes owns the target column
            const int t = ta;
            float xt; bool hit = false;
            if ((t >> 2) == j)                        { xt = xv[t & 3];       hit = true; }
            else if (t >= 64 && ((t - 64) >> 2) == j) { xt = xv[4 + (t & 3)]; hit = true; }
            if (hit) {
                acc_xt += xt;
                atomicAdd(&hPos[(t << 8) | bin_of(xt, off)], 1u);
            }
        }

        a0 = c0; a1 = c1; ta = tb;
        c0 = n0; c1 = n1; tb = tn;
    }

    // CE: sum(lse) - 0.9*sum(x_t) - (0.1/128)*sum(x)
    float ce = acc_lse - 0.9f * acc_xt - (0.1f / 128.0f) * acc_sx;
    #pragma unroll
    for (int o = 32; o; o >>= 1) ce += __shfl_xor(ce, o);
    if (lane == 0) wsum[w] = ce;
    __syncthreads();
    if (tid == 0) {
        float s = 0.0f;
        #pragma unroll
        for (int i = 0; i < 16; i++) s += wsum[i];
        atomicAdd(&acc[0], s);
    }

    // Merge LDS histogram -> global hAll via skip-zero packed u64 atomics.
    for (int i = tid; i < NUM_CLASSES * 128; i += 1024) {
        const u32 v = h32[(i >> 7) * HPITCH + (i & 127)];
        if (v) atomicAdd(&hAll[i], (u64)(v & 0xffffu) | ((u64)(v >> 16) << 32));
    }

    // --- device-wide rendezvous ---
    __syncthreads();              // barrier drains each wave's vmcnt -> all block atomics done
    if (tid == 0) {
        __threadfence();
        atomicAdd((u32*)(acc + 3), 1u);
    }
    if (blockIdx.x >= NUM_CLASSES) return;

    if (tid == 0) {
        while (__hip_atomic_load((u32*)(acc + 3), __ATOMIC_ACQUIRE,
                                 __HIP_MEMORY_SCOPE_AGENT) < NBLK)
            __builtin_amdgcn_s_sleep(2);
    }
    __syncthreads();
    __threadfence();

    // Phase 2: this block reduces class k = blockIdx.x. Lane l owns the
    // DESCENDING bins 255-4l..252-4l = u64 words 127-2l (hi,lo), 126-2l (hi,lo).
    if (tid < 64) {
        const int l = tid;
        const int k = blockIdx.x;
        const u64* hPos64 = (const u64*)hPos;
        const u64 wA1 = __hip_atomic_load(&hAll[k * 128 + 127 - 2 * l],
                                          __ATOMIC_RELAXED, __HIP_MEMORY_SCOPE_AGENT);
        const u64 wA0 = __hip_atomic_load(&hAll[k * 128 + 126 - 2 * l],
                                          __ATOMIC_RELAXED, __HIP_MEMORY_SCOPE_AGENT);
        const u64 wP1 = __hip_atomic_load(&hPos64[k * 128 + 127 - 2 * l],
                                          __ATOMIC_RELAXED, __HIP_MEMORY_SCOPE_AGENT);
        const u64 wP0 = __hip_atomic_load(&hPos64[k * 128 + 126 - 2 * l],
                                          __ATOMIC_RELAXED, __HIP_MEMORY_SCOPE_AGENT);
        const u32 a[4] = {(u32)(wA1 >> 32), (u32)wA1, (u32)(wA0 >> 32), (u32)wA0};
        const u32 p[4] = {(u32)(wP1 >> 32), (u32)wP1, (u32)(wP0 >> 32), (u32)wP0};

        const u32 la = a[0] + a[1] + a[2] + a[3];
        const u32 lp = p[0] + p[1] + p[2] + p[3];

        u32 ia = la, ip = lp;
        #pragma unroll
        for (int o = 1; o < 64; o <<= 1) {
            const u32 tA = __shfl_up(ia, o);
            const u32 tP = __shfl_up(ip, o);
            if (l >= o) { ia += tA; ip += tP; }
        }
        const u32 P = __shfl(ip, 63);
        const u32 T = __shfl(ia, 63);
        const float Pm = fmaxf((float)P, 1.0f);
        const float Fm = fmaxf((float)(T - P), 1.0f);

        int cumA = (int)(ia - la), cumP = (int)(ip - lp);  // exclusive prefixes
        float contrib = 0.0f;
        #pragma unroll
        for (int i = 0; i < 4; i++) {
            const int f = (int)a[i] - (int)p[i];
            if (f > 0) {
                const float fpr0 = (float)(cumA - cumP) / Fm;
                if (fpr0 < MAX_FPR) {
                    const float tpr0 = (float)cumP / Pm;
                    const float tpr1 = (float)(cumP + (int)p[i]) / Pm;
                    const float fpr1 = (float)(cumA - cumP + f) / Fm;
                    if (fpr1 <= MAX_FPR) {
                        contrib += (fpr1 - fpr0) * 0.5f * (tpr0 + tpr1);
                    } else {
                        const float tfrac = (MAX_FPR - fpr0) / (fpr1 - fpr0);
                        const float tprc  = tpr0 + tfrac * (tpr1 - tpr0);
                        contrib += (MAX_FPR - fpr0) * 0.5f * (tpr0 + tprc);
                    }
                }
            }
            cumA += (int)a[i]; cumP += (int)p[i];
        }

        #pragma unroll
        for (int o = 32; o; o >>= 1) contrib += __shfl_xor(contrib, o);

        if (l == 0) {
            if (P > 0u) {
                atomicAdd(&acc[1], contrib);
                atomicAdd(&acc[2], 1.0f);
            }
            __threadfence();
            const u32 done = atomicAdd((u32*)(acc + 4), 1u);
            if (done == NUM_CLASSES - 1) {
                const float ces = atomicAdd(&acc[0], 0.0f);
                const float ps  = atomicAdd(&acc[1], 0.0f);
                const float vs  = atomicAdd(&acc[2], 0.0f);
                const float cem  = ces * (1.0f / (float)N_SAMPLES);
                const float pauc = ps / fmaxf(vs, 1.0f);
                out[0] = 0.5f * cem + 0.5f * (1.0f - pauc * pauc);
            }
        }
    }
}

extern "C" void kernel_launch(void* const* d_in, const int* in_sizes, int n_in,
                              void* d_out, int out_size, void* d_ws, size_t ws_size,
                              hipStream_t stream)
{
    const float* pred = (const float*)d_in[0];
    const int*   tgt  = (const int*)d_in[1];

    char* ws = (char*)d_ws;
    u64*   hAll = (u64*)ws;                    // 128 KB
    u32*   hPos = (u32*)(ws + 131072);         // 128 KB
    float* acc  = (float*)(ws + 262144);       // 32 B

    hipMemsetAsync(ws, 0, 262144 + 32, stream);
    fused_all<<<NBLK, 1024, 0, stream>>>(pred, tgt, hAll, hPos, acc, (float*)d_out);
}

// Round 7
// 111.149 us; speedup vs baseline: 1.3880x; 1.3880x over previous
//
#include <hip/hip_runtime.h>
#include <math.h>

#define N_SAMPLES 131072
#define NUM_CLASSES 128
#define NB 256
#define MAX_FPR 0.7f          // 1 - RECALL_THRESHOLD
#define NBLK 256              // fused grid: 1 block/CU
#define ROWS_PER_BLK 512
#define HPITCH 129            // class row pitch in LDS words (+1 pad)
#define PART_WORDS (NUM_CLASSES * 128)   // 16384 u32 per block partial

typedef unsigned long long u64;
typedef unsigned int u32;

// bin(x; L) = floor((x - L + 14) * 16) clamped to [0,255]. Identical
// expression for the positive and the all histogram.
__device__ __forceinline__ int bin_of(float x, float off /* (14-lse)*16 */) {
    int b = (int)__fmaf_rn(x, 16.0f, off);
    return min(max(b, 0), NB - 1);
}

// ---------------------------------------------------------------------------
// Fused phase 1: block = 512 rows, full 128x256 LDS histogram (u16 pairs in
// u32; per-block counts <= 512, no carry). 16 lanes/row, 8 cols/lane via two
// coalesced float4 loads; 2-deep software pipeline.
//
// Bank-conflict fix: class c's bin-word bw lives at c*129 + ((bw + j) & 127),
// j = (c>>2)&15. Bank = (c + bw + j) mod 32 = (5j + q + bw) mod 32: the 16
// j-values map to 16 DISTINCT banks (gcd(5,32)=1), vs <=8 banks unswizzled
// (stride-4 classes). Writeout un-rotates. Partials are plain coalesced
// stores (no global atomics, no rendezvous — r6's regression).
// ---------------------------------------------------------------------------
__global__ __launch_bounds__(1024, 4) void fused_kernel(
    const float* __restrict__ pred, const int* __restrict__ tgt,
    u32* __restrict__ hPos,      // [128][256] global, pre-zeroed
    u32* __restrict__ part,      // [NBLK][16384] non-atomic partials
    float* __restrict__ acc)     // [0] = ce sum
{
    __shared__ u32 h32[NUM_CLASSES * HPITCH];   // 66048 B
    __shared__ float wsum[16];

    const int tid  = threadIdx.x;
    const int w    = tid >> 6;        // wave 0..15
    const int lane = tid & 63;
    const int j    = lane & 15;       // lane within row
    const int rs   = lane >> 4;       // row sub-index 0..3

    for (int i = tid; i < NUM_CLASSES * HPITCH; i += 1024) h32[i] = 0u;
    __syncthreads();

    const int rowBase = blockIdx.x * ROWS_PER_BLK + w * 4 + rs;
    float acc_lse = 0.0f, acc_xt = 0.0f, acc_sx = 0.0f;

    // 2-deep pipeline over 8 passes (row stride 64 per pass)
    const float* r0p = pred + (size_t)rowBase * 128;
    float4 a0 = *(const float4*)(r0p + j * 4);
    float4 a1 = *(const float4*)(r0p + 64 + j * 4);
    int    ta = tgt[rowBase];
    const float* r1p = r0p + (size_t)64 * 128;
    float4 c0 = *(const float4*)(r1p + j * 4);
    float4 c1 = *(const float4*)(r1p + 64 + j * 4);
    int    tb = tgt[rowBase + 64];

    #pragma unroll
    for (int p = 0; p < 8; p++) {
        float4 n0, n1; int tn = 0;
        if (p < 6) {
            const float* rn = pred + (size_t)(rowBase + (p + 2) * 64) * 128;
            n0 = *(const float4*)(rn + j * 4);
            n1 = *(const float4*)(rn + 64 + j * 4);
            tn = tgt[rowBase + (p + 2) * 64];
        }

        float e = __expf(a0.x) + __expf(a0.y) + __expf(a0.z) + __expf(a0.w)
                + __expf(a1.x) + __expf(a1.y) + __expf(a1.z) + __expf(a1.w);
        #pragma unroll
        for (int o = 1; o < 16; o <<= 1) e += __shfl_xor(e, o);
        const float lse = __logf(e);
        const float off = (14.0f - lse) * 16.0f;

        const float xv[8] = {a0.x, a0.y, a0.z, a0.w, a1.x, a1.y, a1.z, a1.w};
        #pragma unroll
        for (int q = 0; q < 8; q++) {
            const int c = (q < 4) ? (j * 4 + q) : (64 + j * 4 + (q - 4));
            const int b = bin_of(xv[q], off);
            const int word = ((b >> 1) + j) & 127;      // swizzle: 16 banks
            atomicAdd(&h32[c * HPITCH + word], (b & 1) ? 65536u : 1u);
        }

        acc_sx  += (xv[0] + xv[1] + xv[2] + xv[3])
                 + (xv[4] + xv[5] + xv[6] + xv[7]);
        acc_lse += lse * 0.0625f;     // 16 lanes/row each add lse/16

        {   // exactly one of the row's 16 lanes owns the target column
            const int t = ta;
            float xt; bool hit = false;
            if ((t >> 2) == j)                        { xt = xv[t & 3];       hit = true; }
            else if (t >= 64 && ((t - 64) >> 2) == j) { xt = xv[4 + (t & 3)]; hit = true; }
            if (hit) {
                acc_xt += xt;
                atomicAdd(&hPos[(t << 8) | bin_of(xt, off)], 1u);
            }
        }

        a0 = c0; a1 = c1; ta = tb;
        c0 = n0; c1 = n1; tb = tn;
    }

    // CE: sum(lse) - 0.9*sum(x_t) - (0.1/128)*sum(x)
    float ce = acc_lse - 0.9f * acc_xt - (0.1f / 128.0f) * acc_sx;
    #pragma unroll
    for (int o = 32; o; o >>= 1) ce += __shfl_xor(ce, o);
    if (lane == 0) wsum[w] = ce;
    __syncthreads();
    if (tid == 0) {
        float s = 0.0f;
        #pragma unroll
        for (int i = 0; i < 16; i++) s += wsum[i];
        atomicAdd(&acc[0], s);
    }

    // un-rotating partial writeout: linear i = c*128 + bw
    u32* outp = part + (size_t)blockIdx.x * PART_WORDS;
    for (int i = tid; i < PART_WORDS; i += 1024) {
        const int c = i >> 7, bw = i & 127;
        outp[i] = h32[c * HPITCH + ((bw + ((c >> 2) & 15)) & 127)];
    }
}

// ---------------------------------------------------------------------------
// Reducer + finalize: one 256-thread block per class. Thread t sums packed
// word (t&127) over half the NBLK partials (coalesced streams, 8-deep MLP),
// LDS merge, wave 0 does the descending-bin scan + clipped trapezoidal pAUC.
// Last-done block writes the final scalar.
// ---------------------------------------------------------------------------
__global__ __launch_bounds__(256) void pauc_reduce(
    const u32* __restrict__ part,
    const u32* __restrict__ hPos,
    float* __restrict__ acc,          // [0]=ce,[1]=pauc,[2]=valid,[3]=done ctr
    float* __restrict__ out)
{
    __shared__ __align__(16) u32 sA[NB];

    const int k    = blockIdx.x;
    const int t    = threadIdx.x;
    const int w    = t & 127;         // packed word within class row
    const int half = t >> 7;          // which half of the block-partials

    u32 lo = 0u, hi = 0u;
    const u32* p0 = part + (size_t)(half * (NBLK / 2)) * PART_WORDS
                         + k * 128 + w;
    #pragma unroll 8
    for (int b = 0; b < NBLK / 2; b++) {
        const u32 q = p0[(size_t)b * PART_WORDS];
        lo += q & 0xffffu; hi += q >> 16;
    }
    if (half == 0) { sA[2 * w] = lo; sA[2 * w + 1] = hi; }
    __syncthreads();
    if (half == 1) { sA[2 * w] += lo; sA[2 * w + 1] += hi; }
    __syncthreads();

    if (t < 64) {
        const int lane = t;
        // lane owns DESCENDING bins 255-4l..252-4l = uint4 at word 63-l, reversed
        const uint4 q  = ((const uint4*)sA)[63 - lane];
        const u32 a[4] = {q.w, q.z, q.y, q.x};
        const uint4 pq = ((const uint4*)(hPos + (k << 8)))[63 - lane];
        const u32 p[4] = {pq.w, pq.z, pq.y, pq.x};

        const u32 la = a[0] + a[1] + a[2] + a[3];
        const u32 lp = p[0] + p[1] + p[2] + p[3];

        u32 ia = la, ip = lp;
        #pragma unroll
        for (int o = 1; o < 64; o <<= 1) {
            const u32 tA = __shfl_up(ia, o);
            const u32 tP = __shfl_up(ip, o);
            if (lane >= o) { ia += tA; ip += tP; }
        }
        const u32 P = __shfl(ip, 63);
        const u32 T = __shfl(ia, 63);
        const float Pm = fmaxf((float)P, 1.0f);
        const float Fm = fmaxf((float)(T - P), 1.0f);

        int cumA = (int)(ia - la), cumP = (int)(ip - lp);  // exclusive prefixes
        float contrib = 0.0f;
        #pragma unroll
        for (int i = 0; i < 4; i++) {
            const int f = (int)a[i] - (int)p[i];
            if (f > 0) {
                const float fpr0 = (float)(cumA - cumP) / Fm;
                if (fpr0 < MAX_FPR) {
                    const float tpr0 = (float)cumP / Pm;
                    const float tpr1 = (float)(cumP + (int)p[i]) / Pm;
                    const float fpr1 = (float)(cumA - cumP + f) / Fm;
                    if (fpr1 <= MAX_FPR) {
                        contrib += (fpr1 - fpr0) * 0.5f * (tpr0 + tpr1);
                    } else {
                        const float tfrac = (MAX_FPR - fpr0) / (fpr1 - fpr0);
                        const float tprc  = tpr0 + tfrac * (tpr1 - tpr0);
                        contrib += (MAX_FPR - fpr0) * 0.5f * (tpr0 + tprc);
                    }
                }
            }
            cumA += (int)a[i]; cumP += (int)p[i];
        }

        #pragma unroll
        for (int o = 32; o; o >>= 1) contrib += __shfl_xor(contrib, o);

        if (lane == 0) {
            if (P > 0u) {
                atomicAdd(&acc[1], contrib);
                atomicAdd(&acc[2], 1.0f);
            }
            __threadfence();
            const u32 done = atomicAdd((u32*)(acc + 3), 1u);
            if (done == NUM_CLASSES - 1) {
                const float ces = atomicAdd(&acc[0], 0.0f);
                const float ps  = atomicAdd(&acc[1], 0.0f);
                const float vs  = atomicAdd(&acc[2], 0.0f);
                const float cem  = ces * (1.0f / (float)N_SAMPLES);
                const float pauc = ps / fmaxf(vs, 1.0f);
                out[0] = 0.5f * cem + 0.5f * (1.0f - pauc * pauc);
            }
        }
    }
}

extern "C" void kernel_launch(void* const* d_in, const int* in_sizes, int n_in,
                              void* d_out, int out_size, void* d_ws, size_t ws_size,
                              hipStream_t stream)
{
    const float* pred = (const float*)d_in[0];
    const int*   tgt  = (const int*)d_in[1];

    char* ws = (char*)d_ws;
    u32*   hPos = (u32*)ws;                    // 128 KB
    float* acc  = (float*)(ws + 131072);       // 32 B (acc[0..3])
    u32*   part = (u32*)(ws + 262144);         // 16 MB partials

    hipMemsetAsync(ws, 0, 131072 + 32, stream);   // hPos + acc

    fused_kernel<<<NBLK, 1024, 0, stream>>>(pred, tgt, hPos, part, acc);
    pauc_reduce<<<NUM_CLASSES, 256, 0, stream>>>(part, hPos, acc, (float*)d_out);
}